// Round 1
// baseline (277.921 us; speedup 1.0000x reference)
//
#include <hip/hip_runtime.h>
#include <hip/hip_bf16.h>

typedef __attribute__((ext_vector_type(8))) short bf16x8;
typedef __attribute__((ext_vector_type(4))) short bf16x4;
typedef __attribute__((ext_vector_type(4))) float f32x4;

#define HS 128
#define ED 1024
#define TT 2048
#define NBATCH 8
#define NROWS (NBATCH * TT)  // 16384

__device__ __forceinline__ short bf16rne(float f) {
    unsigned u = __builtin_bit_cast(unsigned, f);
    u = u + 0x7fffu + ((u >> 16) & 1u);
    return (short)(u >> 16);
}

// ---------- W transpose: [1024][128] f32 -> [128][1024] bf16 ----------
__global__ void k_wtrans(const float* __restrict__ Wk, const float* __restrict__ Wv,
                         short* __restrict__ WkT, short* __restrict__ WvT) {
    const float* W = blockIdx.y ? Wv : Wk;
    short* WT = blockIdx.y ? WvT : WkT;
    __shared__ float tile[16][128];
    const int k0 = blockIdx.x * 16;
    const int t = threadIdx.x;
#pragma unroll
    for (int i = 0; i < 8; ++i) {
        int idx = t + i * 256;
        tile[idx >> 7][idx & 127] = W[(size_t)(k0 + (idx >> 7)) * HS + (idx & 127)];
    }
    __syncthreads();
    const int n = t >> 1;
    const int h = (t & 1) * 8;
    bf16x8 o;
#pragma unroll
    for (int i = 0; i < 8; ++i) o[i] = bf16rne(tile[h + i][n]);
    *reinterpret_cast<bf16x8*>(&WT[(size_t)n * ED + k0 + h]) = o;
}

// ---------- projections: K = x@Wk (row-major bf16), V^T = (x@Wv)^T ----------
__global__ __launch_bounds__(256) void k_proj(
        const float* __restrict__ x,
        const short* __restrict__ WkT, const short* __restrict__ WvT,
        short* __restrict__ Kbuf, short* __restrict__ VT) {
    const int tid = threadIdx.x;
    const int lane = tid & 63;
    const int wv = tid >> 6;           // 4 waves
    const int lr = lane & 15, g = lane >> 4;
    const int m0 = blockIdx.x * 64 + (wv & 1) * 32;   // 32 rows per wave
    const bool isK = (wv >> 1) == 0;   // waves 0,1: K-side; 2,3: V-side
    const short* WT = isK ? WkT : WvT;

    f32x4 acc[2][8];
#pragma unroll
    for (int a = 0; a < 2; ++a)
#pragma unroll
        for (int b = 0; b < 8; ++b) acc[a][b] = (f32x4){0.f, 0.f, 0.f, 0.f};

    for (int ks = 0; ks < 32; ++ks) {
        const int kd = ks * 32 + g * 8;
        bf16x8 afr[2];
#pragma unroll
        for (int mf = 0; mf < 2; ++mf) {
            const float* xp = x + (size_t)(m0 + 16 * mf + lr) * ED + kd;
            f32x4 x0 = *reinterpret_cast<const f32x4*>(xp);
            f32x4 x1 = *reinterpret_cast<const f32x4*>(xp + 4);
            bf16x8 a;
            a[0] = bf16rne(x0[0]); a[1] = bf16rne(x0[1]);
            a[2] = bf16rne(x0[2]); a[3] = bf16rne(x0[3]);
            a[4] = bf16rne(x1[0]); a[5] = bf16rne(x1[1]);
            a[6] = bf16rne(x1[2]); a[7] = bf16rne(x1[3]);
            afr[mf] = a;
        }
#pragma unroll
        for (int nf = 0; nf < 8; ++nf) {
            bf16x8 bfr = *reinterpret_cast<const bf16x8*>(&WT[(size_t)(nf * 16 + lr) * ED + kd]);
            acc[0][nf] = __builtin_amdgcn_mfma_f32_16x16x32_bf16(afr[0], bfr, acc[0][nf], 0, 0, 0);
            acc[1][nf] = __builtin_amdgcn_mfma_f32_16x16x32_bf16(afr[1], bfr, acc[1][nf], 0, 0, 0);
        }
    }

    if (isK) {
        // C/D layout: col = lane&15 (n), row = 4*(lane>>4)+r (m). Row-major K -> 2B stores.
#pragma unroll
        for (int mf = 0; mf < 2; ++mf)
#pragma unroll
            for (int nf = 0; nf < 8; ++nf) {
                const int m = m0 + 16 * mf + 4 * g;
                const int n = nf * 16 + lr;
#pragma unroll
                for (int r = 0; r < 4; ++r)
                    Kbuf[(size_t)(m + r) * HS + n] = bf16rne(acc[mf][nf][r]);
            }
    } else {
        // V^T[b][n][t]: 4 consecutive t per lane -> packed 8B stores.
#pragma unroll
        for (int mf = 0; mf < 2; ++mf)
#pragma unroll
            for (int nf = 0; nf < 8; ++nf) {
                const int m = m0 + 16 * mf + 4 * g;
                const int b = m >> 11, tt = m & (TT - 1);
                const int n = nf * 16 + lr;
                bf16x4 o;
#pragma unroll
                for (int r = 0; r < 4; ++r) o[r] = bf16rne(acc[mf][nf][r]);
                *reinterpret_cast<bf16x4*>(&VT[((size_t)b * HS + n) * TT + tt]) = o;
            }
    }
}

// ---------- flash attention, S^T trick (q = k per reference bug) ----------
__global__ __launch_bounds__(128) void k_attn(
        const short* __restrict__ Kbuf, const short* __restrict__ VT,
        float* __restrict__ out) {
    const int tid = threadIdx.x;
    const int lane = tid & 63;
    const int wv = tid >> 6;           // 2 waves per block
    const int lr = lane & 15, g = lane >> 4;
    const int bid = blockIdx.x;        // 512 blocks
    const int batch = bid & 7;
    const int qt = 63 - (bid >> 3);    // biggest q-tiles first (LPT packing)
    const int q0 = qt * 32 + wv * 16;  // 16 q-rows per wave

    const short* Kb = Kbuf + (size_t)batch * TT * HS;
    const short* Vb = VT + (size_t)batch * HS * TT;

    __shared__ short plds[2][16][72];  // per-wave P^T staging, 144B row stride

    // Q fragments (B operand): Q[q0+j][kd], j=lane&15, contiguous 16B
    bf16x8 qf[4];
#pragma unroll
    for (int ks = 0; ks < 4; ++ks)
        qf[ks] = *reinterpret_cast<const bf16x8*>(&Kb[(size_t)(q0 + lr) * HS + ks * 32 + g * 8]);

    float mrun = -1e30f, lrun = 0.f;
    f32x4 oacc[8];
#pragma unroll
    for (int i = 0; i < 8; ++i) oacc[i] = (f32x4){0.f, 0.f, 0.f, 0.f};

    const float c1 = 0.08838834764831845f * 1.4426950408889634f;  // 1/sqrt(128) * log2(e)
    const int qrow = q0 + lr;
    const int ntiles = (q0 + 16 + 63) >> 6;

    for (int t = 0; t < ntiles; ++t) {
        const int kv0 = t * 64;
        // S^T = K_tile . Q^T  -> C: col=q (lane&15), row=kv (4g+r+16mf)
        f32x4 s[4];
#pragma unroll
        for (int i = 0; i < 4; ++i) s[i] = (f32x4){0.f, 0.f, 0.f, 0.f};
#pragma unroll
        for (int ks = 0; ks < 4; ++ks) {
#pragma unroll
            for (int mf = 0; mf < 4; ++mf) {
                bf16x8 kf = *reinterpret_cast<const bf16x8*>(
                    &Kb[(size_t)(kv0 + mf * 16 + lr) * HS + ks * 32 + g * 8]);
                s[mf] = __builtin_amdgcn_mfma_f32_16x16x32_bf16(kf, qf[ks], s[mf], 0, 0, 0);
            }
        }
        // scale + causal mask + tile max (per-column q == per-lane + 2 shuffles)
        float pv[4][4];
        float tmax = -1e30f;
#pragma unroll
        for (int mf = 0; mf < 4; ++mf)
#pragma unroll
            for (int r = 0; r < 4; ++r) {
                const int kv = kv0 + mf * 16 + 4 * g + r;
                float v = s[mf][r] * c1;
                v = (kv <= qrow) ? v : -1e30f;
                pv[mf][r] = v;
                tmax = fmaxf(tmax, v);
            }
        tmax = fmaxf(tmax, __shfl_xor(tmax, 16));
        tmax = fmaxf(tmax, __shfl_xor(tmax, 32));
        const float mnew = fmaxf(mrun, tmax);
        const float alpha = exp2f(mrun - mnew);
        mrun = mnew;
        float tsum = 0.f;
#pragma unroll
        for (int mf = 0; mf < 4; ++mf)
#pragma unroll
            for (int r = 0; r < 4; ++r) {
                const float p = exp2f(pv[mf][r] - mnew);
                pv[mf][r] = p;
                tsum += p;
            }
        tsum += __shfl_xor(tsum, 16);
        tsum += __shfl_xor(tsum, 32);
        lrun = lrun * alpha + tsum;
#pragma unroll
        for (int i = 0; i < 8; ++i) oacc[i] *= alpha;

        // P^T -> LDS (bf16, packed 8B writes); same-wave, no barrier needed
#pragma unroll
        for (int mf = 0; mf < 4; ++mf) {
            bf16x4 pk;
#pragma unroll
            for (int r = 0; r < 4; ++r) pk[r] = bf16rne(pv[mf][r]);
            *reinterpret_cast<bf16x4*>(&plds[wv][lr][mf * 16 + g * 4]) = pk;
        }
        // O^T += V^T_tile . P^T
#pragma unroll
        for (int ks = 0; ks < 2; ++ks) {
            bf16x8 pf = *reinterpret_cast<const bf16x8*>(&plds[wv][lr][ks * 32 + g * 8]);
#pragma unroll
            for (int mf = 0; mf < 8; ++mf) {
                bf16x8 vf = *reinterpret_cast<const bf16x8*>(
                    &Vb[(size_t)(mf * 16 + lr) * TT + kv0 + ks * 32 + g * 8]);
                oacc[mf] = __builtin_amdgcn_mfma_f32_16x16x32_bf16(vf, pf, oacc[mf], 0, 0, 0);
            }
        }
    }

    const float inv = 1.0f / lrun;
    float* op = out + ((size_t)batch * TT + q0 + lr) * HS;
#pragma unroll
    for (int mf = 0; mf < 8; ++mf) {
        f32x4 o = oacc[mf] * inv;
        *reinterpret_cast<f32x4*>(&op[mf * 16 + g * 4]) = o;
    }
}

extern "C" void kernel_launch(void* const* d_in, const int* in_sizes, int n_in,
                              void* d_out, int out_size, void* d_ws, size_t ws_size,
                              hipStream_t stream) {
    (void)in_sizes; (void)n_in; (void)out_size; (void)ws_size;
    const float* x  = (const float*)d_in[0];
    const float* Wk = (const float*)d_in[1];
    // d_in[2] = W_query: unused (faithful to the reference's q = key(x) bug)
    const float* Wv = (const float*)d_in[3];
    float* out = (float*)d_out;

    char* ws = (char*)d_ws;
    short* Kbuf = (short*)ws;                                    // 4 MiB bf16 [16384][128]
    short* VT   = (short*)(ws + (size_t)NROWS * HS * 2);         // 4 MiB bf16 [8][128][2048]
    short* WkT  = (short*)(ws + 2 * (size_t)NROWS * HS * 2);     // 256 KiB bf16 [128][1024]
    short* WvT  = WkT + (size_t)HS * ED;                         // 256 KiB

    hipLaunchKernelGGL(k_wtrans, dim3(64, 2), dim3(256), 0, stream, Wk, Wv, WkT, WvT);
    hipLaunchKernelGGL(k_proj, dim3(NROWS / 64), dim3(256), 0, stream, x, WkT, WvT, Kbuf, VT);
    hipLaunchKernelGGL(k_attn, dim3(512), dim3(128), 0, stream, Kbuf, VT, out);
}

// Round 2
// 257.608 us; speedup vs baseline: 1.0789x; 1.0789x over previous
//
#include <hip/hip_runtime.h>
#include <hip/hip_bf16.h>

typedef __attribute__((ext_vector_type(8))) short bf16x8;
typedef __attribute__((ext_vector_type(4))) short bf16x4;
typedef __attribute__((ext_vector_type(4))) float f32x4;

#define HS 128
#define ED 1024
#define TT 2048
#define NBATCH 8
#define NROWS (NBATCH * TT)  // 16384
#define CHUNKS 4
#define KVPC (TT / CHUNKS)       // 512 kv per chunk
#define TPC (KVPC / 64)          // 8 tiles per chunk

__device__ __forceinline__ short bf16rne(float f) {
    unsigned u = __builtin_bit_cast(unsigned, f);
    u = u + 0x7fffu + ((u >> 16) & 1u);
    return (short)(u >> 16);
}

// ---------- x fp32 -> bf16 (one pass, BW-bound) ----------
__global__ __launch_bounds__(256) void k_xconv(const float* __restrict__ x,
                                               short* __restrict__ xb) {
    const size_t i = ((size_t)blockIdx.x * 256 + threadIdx.x) * 8;
    f32x4 a = *reinterpret_cast<const f32x4*>(x + i);
    f32x4 b = *reinterpret_cast<const f32x4*>(x + i + 4);
    bf16x8 o;
    o[0] = bf16rne(a[0]); o[1] = bf16rne(a[1]); o[2] = bf16rne(a[2]); o[3] = bf16rne(a[3]);
    o[4] = bf16rne(b[0]); o[5] = bf16rne(b[1]); o[6] = bf16rne(b[2]); o[7] = bf16rne(b[3]);
    *reinterpret_cast<bf16x8*>(xb + i) = o;
}

// ---------- W transpose: [1024][128] f32 -> [128][1024] bf16 ----------
__global__ void k_wtrans(const float* __restrict__ Wk, const float* __restrict__ Wv,
                         short* __restrict__ WkT, short* __restrict__ WvT) {
    const float* W = blockIdx.y ? Wv : Wk;
    short* WT = blockIdx.y ? WvT : WkT;
    __shared__ float tile[16][128];
    const int k0 = blockIdx.x * 16;
    const int t = threadIdx.x;
#pragma unroll
    for (int i = 0; i < 8; ++i) {
        int idx = t + i * 256;
        tile[idx >> 7][idx & 127] = W[(size_t)(k0 + (idx >> 7)) * HS + (idx & 127)];
    }
    __syncthreads();
    const int n = t >> 1;
    const int h = (t & 1) * 8;
    bf16x8 o;
#pragma unroll
    for (int i = 0; i < 8; ++i) o[i] = bf16rne(tile[h + i][n]);
    *reinterpret_cast<bf16x8*>(&WT[(size_t)n * ED + k0 + h]) = o;
}

// ---------- projections: K = xb@Wk (row-major bf16), V^T = (xb@Wv)^T ----------
// 16 rows per wave, 4 waves/block (2 row-tiles x {K,V}), 512 blocks = 2048 waves
__global__ __launch_bounds__(256) void k_proj(
        const short* __restrict__ xb,
        const short* __restrict__ WkT, const short* __restrict__ WvT,
        short* __restrict__ Kbuf, short* __restrict__ VT) {
    const int tid = threadIdx.x;
    const int lane = tid & 63;
    const int wv = tid >> 6;
    const int lr = lane & 15, g = lane >> 4;
    const int rowtile = blockIdx.x * 2 + (wv & 1);
    const int side = wv >> 1;          // 0 = K, 1 = V
    const int m0 = rowtile * 16;
    const short* WT = side ? WvT : WkT;

    f32x4 acc[8];
#pragma unroll
    for (int b = 0; b < 8; ++b) acc[b] = (f32x4){0.f, 0.f, 0.f, 0.f};

#pragma unroll 4
    for (int ks = 0; ks < 32; ++ks) {
        const int kd = ks * 32 + g * 8;
        bf16x8 af = *reinterpret_cast<const bf16x8*>(&xb[(size_t)(m0 + lr) * ED + kd]);
        bf16x8 bfr[8];
#pragma unroll
        for (int nf = 0; nf < 8; ++nf)
            bfr[nf] = *reinterpret_cast<const bf16x8*>(&WT[(size_t)(nf * 16 + lr) * ED + kd]);
#pragma unroll
        for (int nf = 0; nf < 8; ++nf)
            acc[nf] = __builtin_amdgcn_mfma_f32_16x16x32_bf16(af, bfr[nf], acc[nf], 0, 0, 0);
    }

    // C/D layout: col = lane&15 (n), row = 4*(lane>>4)+r (m)
    if (side == 0) {
#pragma unroll
        for (int nf = 0; nf < 8; ++nf) {
            const int m = m0 + 4 * g;
            const int n = nf * 16 + lr;
#pragma unroll
            for (int r = 0; r < 4; ++r)
                Kbuf[(size_t)(m + r) * HS + n] = bf16rne(acc[nf][r]);
        }
    } else {
#pragma unroll
        for (int nf = 0; nf < 8; ++nf) {
            const int m = m0 + 4 * g;
            const int b = m >> 11, tt = m & (TT - 1);
            const int n = nf * 16 + lr;
            bf16x4 o;
#pragma unroll
            for (int r = 0; r < 4; ++r) o[r] = bf16rne(acc[nf][r]);
            *reinterpret_cast<bf16x4*>(&VT[((size_t)b * HS + n) * TT + tt]) = o;
        }
    }
}

// ---------- flash attention partials, split-KV (q = k per reference bug) ----------
// blockIdx.x: (batch, q-tile), blockIdx.y: kv-chunk. 2 waves/block, 16 q-rows/wave.
__global__ __launch_bounds__(128) void k_attn(
        const short* __restrict__ Kbuf, const short* __restrict__ VT,
        float* __restrict__ Opart, float* __restrict__ ml) {
    const int tid = threadIdx.x;
    const int lane = tid & 63;
    const int wv = tid >> 6;
    const int lr = lane & 15, g = lane >> 4;
    const int bid = blockIdx.x;
    const int batch = bid & 7;
    const int qt = 63 - (bid >> 3);    // biggest q-tiles first
    const int q0 = qt * 32 + wv * 16;
    const int chunk = blockIdx.y;

    const short* Kb = Kbuf + (size_t)batch * TT * HS;
    const short* Vb = VT + (size_t)batch * HS * TT;

    __shared__ short plds[2][16][72];  // per-wave P^T staging

    float mrun = -1e30f, lrun = 0.f;
    f32x4 oacc[8];
#pragma unroll
    for (int i = 0; i < 8; ++i) oacc[i] = (f32x4){0.f, 0.f, 0.f, 0.f};

    const int ntiles_total = (q0 + 16 + 63) >> 6;
    const int t_begin = chunk * TPC;
    const int t_end = min((chunk + 1) * TPC, ntiles_total);

    if (t_begin < t_end) {
        // Q fragments (B operand): contiguous 16B per lane
        bf16x8 qf[4];
#pragma unroll
        for (int ks = 0; ks < 4; ++ks)
            qf[ks] = *reinterpret_cast<const bf16x8*>(&Kb[(size_t)(q0 + lr) * HS + ks * 32 + g * 8]);

        const float c1 = 0.08838834764831845f * 1.4426950408889634f;  // 1/sqrt(128)*log2(e)
        const int qrow = q0 + lr;

        for (int t = t_begin; t < t_end; ++t) {
            const int kv0 = t * 64;
            // S^T = K_tile . Q^T  -> C: col=q (lane&15), row=kv (4g+r+16mf)
            f32x4 s[4];
#pragma unroll
            for (int i = 0; i < 4; ++i) s[i] = (f32x4){0.f, 0.f, 0.f, 0.f};
#pragma unroll
            for (int ks = 0; ks < 4; ++ks) {
                bf16x8 kf[4];
#pragma unroll
                for (int mf = 0; mf < 4; ++mf)
                    kf[mf] = *reinterpret_cast<const bf16x8*>(
                        &Kb[(size_t)(kv0 + mf * 16 + lr) * HS + ks * 32 + g * 8]);
#pragma unroll
                for (int mf = 0; mf < 4; ++mf)
                    s[mf] = __builtin_amdgcn_mfma_f32_16x16x32_bf16(kf[mf], qf[ks], s[mf], 0, 0, 0);
            }
            // scale + causal mask + tile max (2 shuffles)
            float pv[4][4];
            float tmax = -1e30f;
#pragma unroll
            for (int mf = 0; mf < 4; ++mf)
#pragma unroll
                for (int r = 0; r < 4; ++r) {
                    const int kv = kv0 + mf * 16 + 4 * g + r;
                    float v = s[mf][r] * c1;
                    v = (kv <= qrow) ? v : -1e30f;
                    pv[mf][r] = v;
                    tmax = fmaxf(tmax, v);
                }
            tmax = fmaxf(tmax, __shfl_xor(tmax, 16));
            tmax = fmaxf(tmax, __shfl_xor(tmax, 32));
            const float mnew = fmaxf(mrun, tmax);
            const float alpha = exp2f(mrun - mnew);
            mrun = mnew;
            float tsum = 0.f;
#pragma unroll
            for (int mf = 0; mf < 4; ++mf)
#pragma unroll
                for (int r = 0; r < 4; ++r) {
                    const float p = exp2f(pv[mf][r] - mnew);
                    pv[mf][r] = p;
                    tsum += p;
                }
            tsum += __shfl_xor(tsum, 16);
            tsum += __shfl_xor(tsum, 32);
            lrun = lrun * alpha + tsum;
#pragma unroll
            for (int i = 0; i < 8; ++i) oacc[i] *= alpha;

            // P^T -> LDS (packed 8B writes); same-wave only, no barrier
#pragma unroll
            for (int mf = 0; mf < 4; ++mf) {
                bf16x4 pk;
#pragma unroll
                for (int r = 0; r < 4; ++r) pk[r] = bf16rne(pv[mf][r]);
                *reinterpret_cast<bf16x4*>(&plds[wv][lr][mf * 16 + g * 4]) = pk;
            }
            // O^T += V^T_tile . P^T  (batch the 8 V loads before the MFMAs)
#pragma unroll
            for (int ks = 0; ks < 2; ++ks) {
                bf16x8 pf = *reinterpret_cast<const bf16x8*>(&plds[wv][lr][ks * 32 + g * 8]);
                bf16x8 vf[8];
#pragma unroll
                for (int mf = 0; mf < 8; ++mf)
                    vf[mf] = *reinterpret_cast<const bf16x8*>(
                        &Vb[(size_t)(mf * 16 + lr) * TT + kv0 + ks * 32 + g * 8]);
#pragma unroll
                for (int mf = 0; mf < 8; ++mf)
                    oacc[mf] = __builtin_amdgcn_mfma_f32_16x16x32_bf16(vf[mf], pf, oacc[mf], 0, 0, 0);
            }
        }
    }

    // store unnormalized partial O^T + (m, l)
    const int row = batch * TT + q0 + lr;
    const size_t pidx = (size_t)chunk * NROWS + row;
    float* op = Opart + pidx * HS;
#pragma unroll
    for (int mf = 0; mf < 8; ++mf)
        *reinterpret_cast<f32x4*>(&op[mf * 16 + g * 4]) = oacc[mf];
    if (lane < 16) {
        ml[pidx * 2] = mrun;
        ml[pidx * 2 + 1] = lrun;
    }
}

// ---------- merge split-KV partials ----------
__global__ __launch_bounds__(256) void k_merge(const float* __restrict__ Opart,
                                               const float* __restrict__ ml,
                                               float* __restrict__ out) {
    const int idx = blockIdx.x * 256 + threadIdx.x;   // 16384*32
    const int row = idx >> 5;
    const int h4 = (idx & 31) * 4;
    float m[CHUNKS], l[CHUNKS];
    float M = -1e30f;
#pragma unroll
    for (int c = 0; c < CHUNKS; ++c) {
        const size_t p = (size_t)c * NROWS + row;
        m[c] = ml[p * 2];
        l[c] = ml[p * 2 + 1];
        M = fmaxf(M, m[c]);
    }
    float denom = 0.f;
    f32x4 o = (f32x4){0.f, 0.f, 0.f, 0.f};
#pragma unroll
    for (int c = 0; c < CHUNKS; ++c) {
        const float w = exp2f(m[c] - M);
        denom += w * l[c];
        f32x4 p = *reinterpret_cast<const f32x4*>(&Opart[((size_t)c * NROWS + row) * HS + h4]);
        o += p * w;
    }
    const float inv = 1.0f / denom;
    *reinterpret_cast<f32x4*>(&out[(size_t)row * HS + h4]) = o * inv;
}

extern "C" void kernel_launch(void* const* d_in, const int* in_sizes, int n_in,
                              void* d_out, int out_size, void* d_ws, size_t ws_size,
                              hipStream_t stream) {
    (void)in_sizes; (void)n_in; (void)out_size; (void)ws_size;
    const float* x  = (const float*)d_in[0];
    const float* Wk = (const float*)d_in[1];
    // d_in[2] = W_query: unused (faithful to the reference's q = key(x) bug)
    const float* Wv = (const float*)d_in[3];
    float* out = (float*)d_out;

    char* ws = (char*)d_ws;
    short* Kbuf = (short*)ws;                                    // 4 MiB
    short* VT   = (short*)(ws + (size_t)NROWS * HS * 2);         // 4 MiB
    short* WkT  = (short*)(ws + 2 * (size_t)NROWS * HS * 2);     // 256 KiB
    short* WvT  = WkT + (size_t)HS * ED;                         // 256 KiB
    short* xb   = WvT + (size_t)HS * ED;                         // 32 MiB bf16 x
    float* Opart = (float*)(xb + (size_t)NROWS * ED);            // 32 MiB
    float* mlb   = Opart + (size_t)CHUNKS * NROWS * HS;          // 512 KiB

    hipLaunchKernelGGL(k_xconv, dim3(NROWS * ED / (256 * 8)), dim3(256), 0, stream, x, xb);
    hipLaunchKernelGGL(k_wtrans, dim3(64, 2), dim3(256), 0, stream, Wk, Wv, WkT, WvT);
    hipLaunchKernelGGL(k_proj, dim3(NROWS / 32), dim3(256), 0, stream, xb, WkT, WvT, Kbuf, VT);
    hipLaunchKernelGGL(k_attn, dim3(512, CHUNKS), dim3(128), 0, stream, Kbuf, VT, Opart, mlb);
    hipLaunchKernelGGL(k_merge, dim3(NROWS * 32 / 256), dim3(256), 0, stream, Opart, mlb, out);
}

// Round 3
// 163.428 us; speedup vs baseline: 1.7006x; 1.5763x over previous
//
#include <hip/hip_runtime.h>
#include <hip/hip_bf16.h>

typedef __attribute__((ext_vector_type(8))) short bf16x8;
typedef __attribute__((ext_vector_type(4))) short bf16x4;
typedef __attribute__((ext_vector_type(4))) float f32x4;

#define HS 128
#define ED 1024
#define TT 2048
#define NBATCH 8
#define NROWS (NBATCH * TT)  // 16384
#define CHUNKS 4             // max kv chunks of 512
#define TPC 8                // 64-kv tiles per chunk

__device__ __forceinline__ short bf16rne(float f) {
    unsigned u = __builtin_bit_cast(unsigned, f);
    u = u + 0x7fffu + ((u >> 16) & 1u);
    return (short)(u >> 16);
}

// async global->LDS, 16B per lane. LDS dest must be wave-uniform (HW adds lane*16).
__device__ __forceinline__ void gl_lds16(const void* g, void* l) {
    __builtin_amdgcn_global_load_lds(
        (const __attribute__((address_space(1))) unsigned int*)g,
        (__attribute__((address_space(3))) unsigned int*)l, 16, 0, 0);
}

// Stage NCALLS*4KB of a row-major global tile into XOR-swizzled LDS.
// LDS row = 1<<RBL2 bytes; swizzle: colU = colS ^ ((row&7)<<4) (involution).
// Linear LDS dest + inverse-swizzled global source (rule 21).
template <int NCALLS, int RBL2>
__device__ __forceinline__ void stage_tile(const char* gbase, void* lds,
                                           int gpitch, int tid, int wv) {
#pragma unroll
    for (int c = 0; c < NCALLS; ++c) {
        const int o = c * 4096 + tid * 16;
        const int row = o >> RBL2;
        const int colU = (o & ((1 << RBL2) - 1)) ^ ((row & 7) << 4);
        const char* g = gbase + (size_t)row * gpitch + colU;
        char* l = (char*)lds + c * 4096 + wv * 1024;  // wave-uniform
        gl_lds16(g, l);
    }
}

// swizzled ds_read of a bf16x8 fragment; RB = row bytes (128 or 256)
__device__ __forceinline__ bf16x8 lds_rd7(const short* lds, int row, int colE) {
    const int o = (row << 7) + (((colE * 2) & 127) ^ ((row & 7) << 4));
    return *reinterpret_cast<const bf16x8*>((const char*)lds + o);
}
__device__ __forceinline__ bf16x8 lds_rd8(const short* lds, int row, int colE) {
    const int o = (row << 8) + (((colE * 2) & 255) ^ ((row & 7) << 4));
    return *reinterpret_cast<const bf16x8*>((const char*)lds + o);
}

// ---------- W transpose: [1024][128] f32 -> [128][1024] bf16 ----------
__global__ void k_wtrans(const float* __restrict__ Wk, const float* __restrict__ Wv,
                         short* __restrict__ WkT, short* __restrict__ WvT) {
    const float* W = blockIdx.y ? Wv : Wk;
    short* WT = blockIdx.y ? WvT : WkT;
    __shared__ float tile[16][128];
    const int k0 = blockIdx.x * 16;
    const int t = threadIdx.x;
#pragma unroll
    for (int i = 0; i < 8; ++i) {
        int idx = t + i * 256;
        tile[idx >> 7][idx & 127] = W[(size_t)(k0 + (idx >> 7)) * HS + (idx & 127)];
    }
    __syncthreads();
    const int n = t >> 1;
    const int h = (t & 1) * 8;
    bf16x8 o;
#pragma unroll
    for (int i = 0; i < 8; ++i) o[i] = bf16rne(tile[h + i][n]);
    *reinterpret_cast<bf16x8*>(&WT[(size_t)n * ED + k0 + h]) = o;
}

// ---------- projection: one side per block. grid (2 sides, 256 row-tiles) ----------
// 64 tokens/block, 4 waves x 16 rows. x fp32 reg-staged->bf16 LDS; W gl_lds-staged.
__global__ __launch_bounds__(256) void k_proj(
        const float* __restrict__ x,
        const short* __restrict__ WkT, const short* __restrict__ WvT,
        short* __restrict__ Kbuf, short* __restrict__ VT) {
    __shared__ short xl[2][64 * 64];    // 8KB each, swizzled, row=128B
    __shared__ short wl[2][128 * 64];   // 16KB each, swizzled, row=128B

    const int tid = threadIdx.x;
    const int lane = tid & 63;
    const int wv = tid >> 6;
    const int lr = lane & 15, g = lane >> 4;
    const int side = blockIdx.x;        // 0 = K, 1 = V
    const int r0 = blockIdx.y * 64;
    const short* WT = side ? WvT : WkT;

    f32x4 acc[8];
#pragma unroll
    for (int i = 0; i < 8; ++i) acc[i] = (f32x4){0.f, 0.f, 0.f, 0.f};

    f32x4 xa[2][2];
    int xo[2], xrow[2], xcolU[2];
#pragma unroll
    for (int j = 0; j < 2; ++j) {
        xo[j] = tid * 32 + j * 16;
        xrow[j] = xo[j] >> 7;
        xcolU[j] = (xo[j] & 127) ^ ((xrow[j] & 7) << 4);
    }

#define XLOAD(s)                                                                    \
    {                                                                               \
        const int k0_ = (s) * 64;                                                   \
        _Pragma("unroll") for (int j = 0; j < 2; ++j) {                             \
            const float* sp = x + (size_t)(r0 + xrow[j]) * ED + k0_ + (xcolU[j] >> 1); \
            xa[j][0] = *reinterpret_cast<const f32x4*>(sp);                         \
            xa[j][1] = *reinterpret_cast<const f32x4*>(sp + 4);                     \
        }                                                                           \
    }
#define XWRITE(buf)                                                                 \
    {                                                                               \
        _Pragma("unroll") for (int j = 0; j < 2; ++j) {                             \
            bf16x8 pk;                                                              \
            _Pragma("unroll") for (int i = 0; i < 8; ++i)                           \
                pk[i] = bf16rne(xa[j][i >> 2][i & 3]);                              \
            *reinterpret_cast<bf16x8*>((char*)&xl[buf][0] + xo[j]) = pk;            \
        }                                                                           \
    }

    // prologue: stage step 0
    XLOAD(0);
    stage_tile<4, 7>((const char*)WT, &wl[0][0], ED * 2, tid, wv);
    XWRITE(0);
    __syncthreads();

    for (int s = 0; s < 16; ++s) {
        const int cur = s & 1;
        if (s + 1 < 16) {
            XLOAD(s + 1);
            stage_tile<4, 7>((const char*)WT + (size_t)(s + 1) * 128, &wl[cur ^ 1][0],
                             ED * 2, tid, wv);
        }
        // compute from xl[cur], wl[cur]
        bf16x8 af[2];
#pragma unroll
        for (int ks = 0; ks < 2; ++ks)
            af[ks] = lds_rd7(&xl[cur][0], wv * 16 + lr, ks * 32 + g * 8);
#pragma unroll
        for (int ks = 0; ks < 2; ++ks)
#pragma unroll
            for (int nf = 0; nf < 8; ++nf) {
                bf16x8 bfr = lds_rd7(&wl[cur][0], nf * 16 + lr, ks * 32 + g * 8);
                acc[nf] = __builtin_amdgcn_mfma_f32_16x16x32_bf16(af[ks], bfr, acc[nf], 0, 0, 0);
            }
        if (s + 1 < 16) XWRITE(cur ^ 1);
        __syncthreads();
    }
#undef XLOAD
#undef XWRITE

    // epilogue: C col = n (lane&15 + 16nf), row = token (4g+r)
    const int mb = r0 + wv * 16 + 4 * g;
    if (side == 0) {
#pragma unroll
        for (int nf = 0; nf < 8; ++nf) {
            const int n = nf * 16 + lr;
#pragma unroll
            for (int r = 0; r < 4; ++r)
                Kbuf[(size_t)(mb + r) * HS + n] = bf16rne(acc[nf][r]);
        }
    } else {
        const int b = mb >> 11, tt = mb & (TT - 1);
#pragma unroll
        for (int nf = 0; nf < 8; ++nf) {
            const int n = nf * 16 + lr;
            bf16x4 o;
#pragma unroll
            for (int r = 0; r < 4; ++r) o[r] = bf16rne(acc[nf][r]);
            *reinterpret_cast<bf16x4*>(&VT[((size_t)b * HS + n) * TT + tt]) = o;
        }
    }
}

// ---------- flash attention partials (q = k per reference bug) ----------
// 640 flat work items (batch, 64-row q-tile, kv-chunk), 4 waves x 16 q-rows.
// K double-buffered LDS, V single-buffered (mid-tile barrier), all gl_lds-staged.
__global__ __launch_bounds__(256) void k_attn(
        const short* __restrict__ Kbuf, const short* __restrict__ VT,
        float* __restrict__ Opart, float* __restrict__ ml) {
    __shared__ short kl[2][64 * 128];   // 16KB each, swizzled, row=256B
    __shared__ short vl[128 * 64];      // 16KB, swizzled, row=128B
    __shared__ short plds[4][16][72];   // per-wave P^T staging

    const int tid = threadIdx.x;
    const int lane = tid & 63;
    const int wv = tid >> 6;
    const int lr = lane & 15, g = lane >> 4;

    const int bid = blockIdx.x;
    const int b = bid & 7;
    const int w = bid >> 3;             // 0..79, heavy-ish first
    int c, qt;
    if (w < 32)      { c = 0; qt = 31 - w; }
    else if (w < 56) { c = 1; qt = 31 - (w - 32); }
    else if (w < 72) { c = 2; qt = 31 - (w - 56); }
    else             { c = 3; qt = 31 - (w - 72); }
    const int t_begin = c * TPC;
    const int t_end = min(t_begin + TPC, qt + 1);

    const short* Kb = Kbuf + (size_t)b * TT * HS;
    const short* Vb = VT + (size_t)b * HS * TT;
    const int q0 = qt * 64 + wv * 16;

    // Q fragments (B operand), contiguous 16B per lane
    bf16x8 qf[4];
#pragma unroll
    for (int ks = 0; ks < 4; ++ks)
        qf[ks] = *reinterpret_cast<const bf16x8*>(&Kb[(size_t)(q0 + lr) * HS + ks * 32 + g * 8]);

    stage_tile<4, 8>((const char*)(Kb + (size_t)t_begin * 64 * HS), &kl[0][0], HS * 2, tid, wv);
    __syncthreads();

    float mrun = -1e30f, lrun = 0.f;
    f32x4 oacc[8];
#pragma unroll
    for (int i = 0; i < 8; ++i) oacc[i] = (f32x4){0.f, 0.f, 0.f, 0.f};

    const float c1 = 0.08838834764831845f * 1.4426950408889634f;  // 1/sqrt(128)*log2(e)
    const int qrow = q0 + lr;
    int cur = 0;

    for (int t = t_begin; t < t_end; ++t) {
        const int kv0 = t * 64;
        stage_tile<4, 7>((const char*)(Vb + kv0), vl, TT * 2, tid, wv);
        if (t + 1 < t_end)
            stage_tile<4, 8>((const char*)(Kb + (size_t)(kv0 + 64) * HS), &kl[cur ^ 1][0],
                             HS * 2, tid, wv);

        // S^T = K_tile . Q^T  -> C: col=q (lane&15), row=kv (4g+r+16mf)
        f32x4 s[4];
#pragma unroll
        for (int i = 0; i < 4; ++i) s[i] = (f32x4){0.f, 0.f, 0.f, 0.f};
#pragma unroll
        for (int ks = 0; ks < 4; ++ks) {
            bf16x8 kf[4];
#pragma unroll
            for (int mf = 0; mf < 4; ++mf)
                kf[mf] = lds_rd8(&kl[cur][0], mf * 16 + lr, ks * 32 + g * 8);
#pragma unroll
            for (int mf = 0; mf < 4; ++mf)
                s[mf] = __builtin_amdgcn_mfma_f32_16x16x32_bf16(kf[mf], qf[ks], s[mf], 0, 0, 0);
        }
        // scale + causal mask + online softmax (2 shuffles per reduce)
        float pv[4][4];
        float tmax = -1e30f;
#pragma unroll
        for (int mf = 0; mf < 4; ++mf)
#pragma unroll
            for (int r = 0; r < 4; ++r) {
                const int kv = kv0 + mf * 16 + 4 * g + r;
                float v = s[mf][r] * c1;
                v = (kv <= qrow) ? v : -1e30f;
                pv[mf][r] = v;
                tmax = fmaxf(tmax, v);
            }
        tmax = fmaxf(tmax, __shfl_xor(tmax, 16));
        tmax = fmaxf(tmax, __shfl_xor(tmax, 32));
        const float mnew = fmaxf(mrun, tmax);
        const float alpha = exp2f(mrun - mnew);
        mrun = mnew;
        float tsum = 0.f;
#pragma unroll
        for (int mf = 0; mf < 4; ++mf)
#pragma unroll
            for (int r = 0; r < 4; ++r) {
                const float p = exp2f(pv[mf][r] - mnew);
                pv[mf][r] = p;
                tsum += p;
            }
        tsum += __shfl_xor(tsum, 16);
        tsum += __shfl_xor(tsum, 32);
        lrun = lrun * alpha + tsum;
#pragma unroll
        for (int i = 0; i < 8; ++i) oacc[i] *= alpha;

        __syncthreads();  // V(t) staged; kl[cur^1] also drained (over-sync, harmless)

        // P^T -> plds (wave-private, no barrier needed)
#pragma unroll
        for (int mf = 0; mf < 4; ++mf) {
            bf16x4 pk;
#pragma unroll
            for (int r = 0; r < 4; ++r) pk[r] = bf16rne(pv[mf][r]);
            *reinterpret_cast<bf16x4*>(&plds[wv][lr][mf * 16 + g * 4]) = pk;
        }
        // O^T += V^T_tile . P^T
#pragma unroll
        for (int ks = 0; ks < 2; ++ks) {
            bf16x8 pf = *reinterpret_cast<const bf16x8*>(&plds[wv][lr][ks * 32 + g * 8]);
            bf16x8 vf[8];
#pragma unroll
            for (int mf = 0; mf < 8; ++mf)
                vf[mf] = lds_rd7(vl, mf * 16 + lr, ks * 32 + g * 8);
#pragma unroll
            for (int mf = 0; mf < 8; ++mf)
                oacc[mf] = __builtin_amdgcn_mfma_f32_16x16x32_bf16(vf[mf], pf, oacc[mf], 0, 0, 0);
        }
        __syncthreads();  // protect vl / kl[cur] before next iteration's staging
        cur ^= 1;
    }

    // store unnormalized partial O^T + (m, l)
    const int row = b * TT + q0 + lr;
    const size_t pidx = (size_t)c * NROWS + row;
    float* op = Opart + pidx * HS;
#pragma unroll
    for (int mf = 0; mf < 8; ++mf)
        *reinterpret_cast<f32x4*>(&op[mf * 16 + g * 4]) = oacc[mf];
    if (lane < 16) {
        ml[pidx * 2] = mrun;
        ml[pidx * 2 + 1] = lrun;
    }
}

// ---------- merge split-KV partials (guard unwritten chunks) ----------
__global__ __launch_bounds__(256) void k_merge(const float* __restrict__ Opart,
                                               const float* __restrict__ ml,
                                               float* __restrict__ out) {
    const int idx = blockIdx.x * 256 + threadIdx.x;  // NROWS*32
    const int row = idx >> 5;
    const int h4 = (idx & 31) * 4;
    const int qt64 = (row & (TT - 1)) >> 6;
    const int nvalid = (qt64 >> 3) + 1;  // ceil((qt64+1)/8)
    float m[CHUNKS], l[CHUNKS];
    float M = -1e30f;
#pragma unroll
    for (int c = 0; c < CHUNKS; ++c) {
        const bool valid = c < nvalid;
        const size_t p = (size_t)c * NROWS + row;
        m[c] = valid ? ml[p * 2] : -1e30f;
        l[c] = valid ? ml[p * 2 + 1] : 0.f;
        M = fmaxf(M, m[c]);
    }
    float denom = 0.f;
    f32x4 o = (f32x4){0.f, 0.f, 0.f, 0.f};
#pragma unroll
    for (int c = 0; c < CHUNKS; ++c) {
        const bool valid = c < nvalid;
        const float wgt = valid ? exp2f(m[c] - M) : 0.f;
        denom += wgt * l[c];
        if (valid) {
            f32x4 p = *reinterpret_cast<const f32x4*>(
                &Opart[((size_t)c * NROWS + row) * HS + h4]);
            o += p * wgt;
        }
    }
    const float inv = 1.0f / denom;
    *reinterpret_cast<f32x4*>(&out[(size_t)row * HS + h4]) = o * inv;
}

extern "C" void kernel_launch(void* const* d_in, const int* in_sizes, int n_in,
                              void* d_out, int out_size, void* d_ws, size_t ws_size,
                              hipStream_t stream) {
    (void)in_sizes; (void)n_in; (void)out_size; (void)ws_size;
    const float* x  = (const float*)d_in[0];
    const float* Wk = (const float*)d_in[1];
    // d_in[2] = W_query: unused (faithful to the reference's q = key(x) bug)
    const float* Wv = (const float*)d_in[3];
    float* out = (float*)d_out;

    char* ws = (char*)d_ws;
    short* Kbuf = (short*)ws;                                    // 4 MiB bf16 [16384][128]
    short* VT   = (short*)(ws + (size_t)NROWS * HS * 2);         // 4 MiB bf16 [8][128][2048]
    short* WkT  = (short*)(ws + 2 * (size_t)NROWS * HS * 2);     // 256 KiB
    short* WvT  = WkT + (size_t)HS * ED;                         // 256 KiB
    float* Opart = (float*)(WvT + (size_t)HS * ED);              // 32 MiB
    float* mlb   = Opart + (size_t)CHUNKS * NROWS * HS;          // 512 KiB

    hipLaunchKernelGGL(k_wtrans, dim3(64, 2), dim3(256), 0, stream, Wk, Wv, WkT, WvT);
    hipLaunchKernelGGL(k_proj, dim3(2, NROWS / 64), dim3(256), 0, stream, x, WkT, WvT, Kbuf, VT);
    hipLaunchKernelGGL(k_attn, dim3(640), dim3(256), 0, stream, Kbuf, VT, Opart, mlb);
    hipLaunchKernelGGL(k_merge, dim3(NROWS * 32 / 256), dim3(256), 0, stream, Opart, mlb, out);
}